// Round 1
// baseline (1382.465 us; speedup 1.0000x reference)
//
#include <hip/hip_runtime.h>
#include <math.h>

#define NN 100000
#define NE 600000
#define DD 128

// ---------------- zero workspace (msg + deg) ----------------
__global__ void zero_kernel(float* __restrict__ p, int n) {
    int i = blockIdx.x * blockDim.x + threadIdx.x;
    int stride = gridDim.x * blockDim.x;
    for (; i < n; i += stride) p[i] = 0.0f;
}

// ---------------- transpose Wl2, Wr2 (128x128 each) ----------------
__global__ void transpose_kernel(const float* __restrict__ Wl,
                                 const float* __restrict__ Wr,
                                 float* __restrict__ WlT,
                                 float* __restrict__ WrT) {
    int t = blockIdx.x * blockDim.x + threadIdx.x;   // 0..16383
    if (t >= DD * DD) return;
    int k = t >> 7;        // row of transposed
    int d = t & 127;       // col of transposed
    WlT[t] = Wl[d * DD + k];
    WrT[t] = Wr[d * DD + k];
}

// ---------------- scatter: msg[dst] += BN(relu(x[src])), deg[dst] += 1 ----------------
// one thread per (edge, 4-float chunk): 32 threads per edge
__global__ __launch_bounds__(256) void scatter_kernel(
    const float* __restrict__ x, const int* __restrict__ ei,
    const float* __restrict__ bn_gamma, const float* __restrict__ bn_beta,
    const float* __restrict__ bn_mean, const float* __restrict__ bn_var,
    float* __restrict__ msg, float* __restrict__ deg)
{
    int tid = blockIdx.x * blockDim.x + threadIdx.x;
    if (tid >= NE * 32) return;
    int e = tid >> 5;
    int c = (tid & 31) << 2;

    int s  = ei[e];        // src
    int dt = ei[NE + e];   // dst

    const float4 xv = *(const float4*)(x + (size_t)s * DD + c);
    const float4 m  = *(const float4*)(bn_mean  + c);
    const float4 v  = *(const float4*)(bn_var   + c);
    const float4 g  = *(const float4*)(bn_gamma + c);
    const float4 b  = *(const float4*)(bn_beta  + c);

    float h0 = (fmaxf(xv.x, 0.f) - m.x) * rsqrtf(v.x + 1e-5f) * g.x + b.x;
    float h1 = (fmaxf(xv.y, 0.f) - m.y) * rsqrtf(v.y + 1e-5f) * g.y + b.y;
    float h2 = (fmaxf(xv.z, 0.f) - m.z) * rsqrtf(v.z + 1e-5f) * g.z + b.z;
    float h3 = (fmaxf(xv.w, 0.f) - m.w) * rsqrtf(v.w + 1e-5f) * g.w + b.w;

    float* mrow = msg + (size_t)dt * DD + c;
    atomicAdd(mrow + 0, h0);
    atomicAdd(mrow + 1, h1);
    atomicAdd(mrow + 2, h2);
    atomicAdd(mrow + 3, h3);

    if ((tid & 31) == 0) atomicAdd(deg + dt, 1.0f);
}

// ---------------- fused GEMM + L2 normalize ----------------
// out = (msg/deg) @ Wl2^T + bl2 + BN(relu(x)) @ Wr2^T ; then row-normalize.
// Block: 128 threads (thread d = output feature d), 16 nodes per block.
#define TVEC 16
__global__ __launch_bounds__(128) void gemm_norm_kernel(
    const float* __restrict__ x, const float* __restrict__ msg,
    const float* __restrict__ deg,
    const float* __restrict__ WlT, const float* __restrict__ WrT,
    const float* __restrict__ bl,
    const float* __restrict__ bn_gamma, const float* __restrict__ bn_beta,
    const float* __restrict__ bn_mean, const float* __restrict__ bn_var,
    float* __restrict__ out)
{
    __shared__ float a[TVEC][2 * DD];   // [t][0:128)=mean row, [t][128:256)=h row
    __shared__ float wsum[2];

    const int d  = threadIdx.x;
    const int n0 = blockIdx.x * TVEC;

    // hoisted BN params for feature d
    const float bm = bn_mean[d];
    const float bs = rsqrtf(bn_var[d] + 1e-5f) * bn_gamma[d];
    const float bb = bn_beta[d];

    // stage mean + h rows for the tile
    for (int t = 0; t < TVEC; ++t) {
        int node = n0 + t;
        float mean_v = 0.f, hv = 0.f;
        if (node < NN) {
            float dg = fmaxf(deg[node], 1.0f);
            mean_v = msg[(size_t)node * DD + d] / dg;
            float xv = x[(size_t)node * DD + d];
            hv = (fmaxf(xv, 0.f) - bm) * bs + bb;
        }
        a[t][d]      = mean_v;
        a[t][DD + d] = hv;
    }
    __syncthreads();

    const float bias = bl[d];
    float acc[TVEC];
#pragma unroll
    for (int t = 0; t < TVEC; ++t) acc[t] = bias;

    for (int k = 0; k < DD; ++k) {
        float wl = WlT[k * DD + d];
        float wr = WrT[k * DD + d];
#pragma unroll
        for (int t = 0; t < TVEC; ++t) {
            acc[t] = fmaf(a[t][k], wl, acc[t]);
            acc[t] = fmaf(a[t][DD + k], wr, acc[t]);
        }
    }

    const int lane = d & 63;
    const int wv   = d >> 6;

    for (int t = 0; t < TVEC; ++t) {
        float val = acc[t];
        float sq  = val * val;
#pragma unroll
        for (int off = 1; off < 64; off <<= 1)
            sq += __shfl_xor(sq, off);
        if (lane == 0) wsum[wv] = sq;
        __syncthreads();
        float total = wsum[0] + wsum[1];
        __syncthreads();
        float nrm = sqrtf(total);
        float r = val / fmaxf(nrm, 1e-12f);
        int node = n0 + t;
        if (node < NN) out[(size_t)node * DD + d] = r;
    }
}

extern "C" void kernel_launch(void* const* d_in, const int* in_sizes, int n_in,
                              void* d_out, int out_size, void* d_ws, size_t ws_size,
                              hipStream_t stream) {
    // inputs (setup_inputs order):
    // 0 x, 1 edge_index, 2 Wl1, 3 bl1, 4 Wr1, 5 Wl2, 6 bl2, 7 Wr2,
    // 8 bn_gamma, 9 bn_beta, 10 bn_mean, 11 bn_var
    const float* x        = (const float*)d_in[0];
    const int*   ei       = (const int*)d_in[1];
    const float* Wl2      = (const float*)d_in[5];
    const float* bl2      = (const float*)d_in[6];
    const float* Wr2      = (const float*)d_in[7];
    const float* bn_gamma = (const float*)d_in[8];
    const float* bn_beta  = (const float*)d_in[9];
    const float* bn_mean  = (const float*)d_in[10];
    const float* bn_var   = (const float*)d_in[11];
    float* out = (float*)d_out;

    // workspace layout
    float* msg = (float*)d_ws;                    // NN*DD
    float* deg = msg + (size_t)NN * DD;           // NN
    float* WlT = deg + NN;                        // DD*DD
    float* WrT = WlT + DD * DD;                   // DD*DD

    // 1) zero msg+deg (contiguous)
    {
        int n = NN * DD + NN;
        int blocks = 4096;
        zero_kernel<<<blocks, 256, 0, stream>>>(msg, n);
    }
    // 2) transpose weights (independent of zero, same stream = ordered anyway)
    {
        int n = DD * DD;
        transpose_kernel<<<(n + 255) / 256, 256, 0, stream>>>(Wl2, Wr2, WlT, WrT);
    }
    // 3) scatter
    {
        int total = NE * 32;
        scatter_kernel<<<(total + 255) / 256, 256, 0, stream>>>(
            x, ei, bn_gamma, bn_beta, bn_mean, bn_var, msg, deg);
    }
    // 4) fused gemm + normalize
    {
        int blocks = (NN + TVEC - 1) / TVEC;
        gemm_norm_kernel<<<blocks, 128, 0, stream>>>(
            x, msg, deg, WlT, WrT, bl2,
            bn_gamma, bn_beta, bn_mean, bn_var, out);
    }
}

// Round 3
// 420.705 us; speedup vs baseline: 3.2861x; 3.2861x over previous
//
#include <hip/hip_runtime.h>
#include <math.h>

#define NN 100000
#define NE 600000
#define DD 128

// ---------------- zero ints ----------------
__global__ void zero_int_kernel(int* __restrict__ p, int n) {
    int i = blockIdx.x * blockDim.x + threadIdx.x;
    if (i < n) p[i] = 0;
}

// ---------------- histogram of dst ----------------
__global__ void hist_kernel(const int* __restrict__ ei, int* __restrict__ counts) {
    int e = blockIdx.x * blockDim.x + threadIdx.x;
    if (e < NE) atomicAdd(&counts[ei[NE + e]], 1);
}

// ---------------- two-level exclusive scan ----------------
__global__ __launch_bounds__(256) void scan1_kernel(const int* __restrict__ counts,
                                                    int* __restrict__ offsets,
                                                    int* __restrict__ partials, int n) {
    __shared__ int tmp[256];
    int i = blockIdx.x * 256 + threadIdx.x;
    int v = (i < n) ? counts[i] : 0;
    tmp[threadIdx.x] = v;
    __syncthreads();
    for (int off = 1; off < 256; off <<= 1) {
        int t = (threadIdx.x >= off) ? tmp[threadIdx.x - off] : 0;
        __syncthreads();
        tmp[threadIdx.x] += t;
        __syncthreads();
    }
    if (i < n) offsets[i] = tmp[threadIdx.x] - v;   // exclusive
    if (threadIdx.x == 255) partials[blockIdx.x] = tmp[255];
}

__global__ __launch_bounds__(512) void scan2_kernel(int* __restrict__ partials, int nb) {
    __shared__ int tmp[512];
    int v = (threadIdx.x < nb) ? partials[threadIdx.x] : 0;
    tmp[threadIdx.x] = v;
    __syncthreads();
    for (int off = 1; off < 512; off <<= 1) {
        int t = (threadIdx.x >= off) ? tmp[threadIdx.x - off] : 0;
        __syncthreads();
        tmp[threadIdx.x] += t;
        __syncthreads();
    }
    if (threadIdx.x < nb) partials[threadIdx.x] = tmp[threadIdx.x] - v;  // exclusive
}

__global__ void scan3_kernel(int* __restrict__ offsets, int* __restrict__ cursor,
                             const int* __restrict__ partials, int n) {
    int i = blockIdx.x * 256 + threadIdx.x;
    if (i < n) {
        int o = offsets[i] + partials[blockIdx.x];
        offsets[i] = o;
        cursor[i]  = o;
    }
    if (i == 0) offsets[n] = NE;
}

// ---------------- reorder: sorted_src ----------------
__global__ void reorder_kernel(const int* __restrict__ ei, int* __restrict__ cursor,
                               int* __restrict__ ssrc) {
    int e = blockIdx.x * blockDim.x + threadIdx.x;
    if (e < NE) {
        int pos = atomicAdd(&cursor[ei[NE + e]], 1);
        ssrc[pos] = ei[e];
    }
}

// ---------------- transpose Wl2, Wr2 ----------------
__global__ void transpose_kernel(const float* __restrict__ Wl,
                                 const float* __restrict__ Wr,
                                 float* __restrict__ WlT,
                                 float* __restrict__ WrT) {
    int t = blockIdx.x * blockDim.x + threadIdx.x;
    if (t >= DD * DD) return;
    int k = t >> 7;
    int d = t & 127;
    WlT[t] = Wl[d * DD + k];
    WrT[t] = Wr[d * DD + k];
}

// ---------------- CSR aggregation: msg[n] = mean_h ----------------
// 2 nodes per 256-thread block; thread d = feature. No atomics.
__global__ __launch_bounds__(256) void aggregate_kernel(
    const float* __restrict__ x, const int* __restrict__ offsets,
    const int* __restrict__ ssrc,
    const float* __restrict__ bn_gamma, const float* __restrict__ bn_beta,
    const float* __restrict__ bn_mean, const float* __restrict__ bn_var,
    float* __restrict__ msg)
{
    int node = blockIdx.x * 2 + (threadIdx.x >> 7);
    int d = threadIdx.x & 127;
    if (node >= NN) return;

    const float bm = bn_mean[d];
    const float bs = rsqrtf(bn_var[d] + 1e-5f) * bn_gamma[d];
    const float bb = bn_beta[d];

    int st = offsets[node], en = offsets[node + 1];
    float sum_relu = 0.f;
    for (int j = st; j < en; ++j) {
        float xv = x[(size_t)ssrc[j] * DD + d];
        sum_relu += fmaxf(xv, 0.f);
    }
    int deg = en - st;
    float mean;
    if (deg > 0) {
        float inv = 1.0f / (float)deg;
        mean = (sum_relu * inv - bm) * bs + bb;   // mean of h == BN applied to mean of relu
    } else {
        mean = 0.f;
    }
    msg[(size_t)node * DD + d] = mean;
}

// ---------------- fused GEMM + L2 normalize ----------------
// out = mean @ Wl2^T + bl2 + h @ Wr2^T ; row-normalize.
// 128 threads, 16 nodes/block. Thread: group g=tid>>5 owns nodes t0..t0+3,
// lane l=tid&31 owns features 4l..4l+3. acc[4][4] register tile.
#define TV 16
__global__ __launch_bounds__(128) void gemm_norm_kernel(
    const float* __restrict__ x, const float* __restrict__ msg,
    const float* __restrict__ WlT, const float* __restrict__ WrT,
    const float* __restrict__ bl,
    const float* __restrict__ bn_gamma, const float* __restrict__ bn_beta,
    const float* __restrict__ bn_mean, const float* __restrict__ bn_var,
    float* __restrict__ out)
{
    __shared__ float a[TV][2 * DD];   // [t][0:128)=mean, [t][128:256)=h
    const int tid = threadIdx.x;
    const int n0 = blockIdx.x * TV;

    // ---- stage (thread d = tid) ----
    {
        const int d = tid;
        const float bm = bn_mean[d];
        const float bs = rsqrtf(bn_var[d] + 1e-5f) * bn_gamma[d];
        const float bb = bn_beta[d];
#pragma unroll
        for (int t = 0; t < TV; ++t) {
            int node = n0 + t;
            a[t][d] = msg[(size_t)node * DD + d];
            float xv = x[(size_t)node * DD + d];
            a[t][DD + d] = (fmaxf(xv, 0.f) - bm) * bs + bb;
        }
    }
    __syncthreads();

    const int g  = tid >> 5;      // 0..3
    const int l  = tid & 31;
    const int d0 = l * 4;
    const int t0 = g * 4;

    const float4 bias4 = *(const float4*)(bl + d0);
    float acc[4][4];
#pragma unroll
    for (int t = 0; t < 4; ++t) {
        acc[t][0] = bias4.x; acc[t][1] = bias4.y;
        acc[t][2] = bias4.z; acc[t][3] = bias4.w;
    }

    for (int k = 0; k < DD; k += 4) {
        float am[4][4], ah[4][4];
#pragma unroll
        for (int t = 0; t < 4; ++t) {
            *(float4*)am[t] = *(const float4*)&a[t0 + t][k];
            *(float4*)ah[t] = *(const float4*)&a[t0 + t][DD + k];
        }
#pragma unroll
        for (int kk = 0; kk < 4; ++kk) {
            const float4 wl = *(const float4*)(WlT + (k + kk) * DD + d0);
            const float4 wr = *(const float4*)(WrT + (k + kk) * DD + d0);
#pragma unroll
            for (int t = 0; t < 4; ++t) {
                float amv = am[t][kk];
                float ahv = ah[t][kk];
                acc[t][0] = fmaf(amv, wl.x, acc[t][0]);
                acc[t][1] = fmaf(amv, wl.y, acc[t][1]);
                acc[t][2] = fmaf(amv, wl.z, acc[t][2]);
                acc[t][3] = fmaf(amv, wl.w, acc[t][3]);
                acc[t][0] = fmaf(ahv, wr.x, acc[t][0]);
                acc[t][1] = fmaf(ahv, wr.y, acc[t][1]);
                acc[t][2] = fmaf(ahv, wr.z, acc[t][2]);
                acc[t][3] = fmaf(ahv, wr.w, acc[t][3]);
            }
        }
    }

    // ---- normalize: reduce across the 32-lane group ----
#pragma unroll
    for (int t = 0; t < 4; ++t) {
        float sq = acc[t][0] * acc[t][0] + acc[t][1] * acc[t][1]
                 + acc[t][2] * acc[t][2] + acc[t][3] * acc[t][3];
#pragma unroll
        for (int off = 1; off < 32; off <<= 1)
            sq += __shfl_xor(sq, off);
        float inv = 1.0f / fmaxf(sqrtf(sq), 1e-12f);
        float4 o;
        o.x = acc[t][0] * inv; o.y = acc[t][1] * inv;
        o.z = acc[t][2] * inv; o.w = acc[t][3] * inv;
        *(float4*)(out + (size_t)(n0 + t0 + t) * DD + d0) = o;
    }
}

extern "C" void kernel_launch(void* const* d_in, const int* in_sizes, int n_in,
                              void* d_out, int out_size, void* d_ws, size_t ws_size,
                              hipStream_t stream) {
    const float* x        = (const float*)d_in[0];
    const int*   ei       = (const int*)d_in[1];
    const float* Wl2      = (const float*)d_in[5];
    const float* bl2      = (const float*)d_in[6];
    const float* Wr2      = (const float*)d_in[7];
    const float* bn_gamma = (const float*)d_in[8];
    const float* bn_beta  = (const float*)d_in[9];
    const float* bn_mean  = (const float*)d_in[10];
    const float* bn_var   = (const float*)d_in[11];
    float* out = (float*)d_out;

    // workspace layout
    float* msg      = (float*)d_ws;                         // NN*DD
    float* WlT      = msg + (size_t)NN * DD;                // DD*DD
    float* WrT      = WlT + DD * DD;                        // DD*DD
    int*   counts   = (int*)(WrT + DD * DD);                // NN
    int*   offsets  = counts + NN;                          // NN+1
    int*   cursor   = offsets + NN + 1;                     // NN
    int*   partials = cursor + NN;                          // 512
    int*   ssrc     = partials + 512;                       // NE

    const int nb_nodes = (NN + 255) / 256;   // 391
    const int nb_edges = (NE + 255) / 256;

    zero_int_kernel<<<nb_nodes, 256, 0, stream>>>(counts, NN);
    hist_kernel<<<nb_edges, 256, 0, stream>>>(ei, counts);
    scan1_kernel<<<nb_nodes, 256, 0, stream>>>(counts, offsets, partials, NN);
    scan2_kernel<<<1, 512, 0, stream>>>(partials, nb_nodes);
    scan3_kernel<<<nb_nodes, 256, 0, stream>>>(offsets, cursor, partials, NN);
    reorder_kernel<<<nb_edges, 256, 0, stream>>>(ei, cursor, ssrc);
    transpose_kernel<<<(DD * DD + 255) / 256, 256, 0, stream>>>(Wl2, Wr2, WlT, WrT);
    aggregate_kernel<<<NN / 2, 256, 0, stream>>>(
        x, offsets, ssrc, bn_gamma, bn_beta, bn_mean, bn_var, msg);
    gemm_norm_kernel<<<NN / TV, 128, 0, stream>>>(
        x, msg, WlT, WrT, bl2, bn_gamma, bn_beta, bn_mean, bn_var, out);
}

// Round 6
// 309.328 us; speedup vs baseline: 4.4693x; 1.3601x over previous
//
#include <hip/hip_runtime.h>
#include <math.h>

#define NN 100000
#define NE 600000
#define DD 128

typedef __attribute__((ext_vector_type(8))) __bf16 bf16x8;
typedef __attribute__((ext_vector_type(4))) float f32x4;

__device__ inline unsigned short f2bf(float f) {
    unsigned int u = __float_as_uint(f);
    unsigned int r = (u + 0x7fffu + ((u >> 16) & 1u)) >> 16;
    return (unsigned short)r;
}

// ---------------- zero ints ----------------
__global__ void zero_int_kernel(int* __restrict__ p, int n) {
    int i = blockIdx.x * blockDim.x + threadIdx.x;
    if (i < n) p[i] = 0;
}

// ---------------- histogram of dst ----------------
__global__ void hist_kernel(const int* __restrict__ ei, int* __restrict__ counts) {
    int e = blockIdx.x * blockDim.x + threadIdx.x;
    if (e < NE) atomicAdd(&counts[ei[NE + e]], 1);
}

// ---------------- two-level exclusive scan ----------------
__global__ __launch_bounds__(256) void scan1_kernel(const int* __restrict__ counts,
                                                    int* __restrict__ offsets,
                                                    int* __restrict__ partials, int n) {
    __shared__ int tmp[256];
    int i = blockIdx.x * 256 + threadIdx.x;
    int v = (i < n) ? counts[i] : 0;
    tmp[threadIdx.x] = v;
    __syncthreads();
    for (int off = 1; off < 256; off <<= 1) {
        int t = (threadIdx.x >= off) ? tmp[threadIdx.x - off] : 0;
        __syncthreads();
        tmp[threadIdx.x] += t;
        __syncthreads();
    }
    if (i < n) offsets[i] = tmp[threadIdx.x] - v;   // exclusive
    if (threadIdx.x == 255) partials[blockIdx.x] = tmp[255];
}

__global__ __launch_bounds__(512) void scan2_kernel(int* __restrict__ partials, int nb) {
    __shared__ int tmp[512];
    int v = (threadIdx.x < nb) ? partials[threadIdx.x] : 0;
    tmp[threadIdx.x] = v;
    __syncthreads();
    for (int off = 1; off < 512; off <<= 1) {
        int t = (threadIdx.x >= off) ? tmp[threadIdx.x - off] : 0;
        __syncthreads();
        tmp[threadIdx.x] += t;
        __syncthreads();
    }
    if (threadIdx.x < nb) partials[threadIdx.x] = tmp[threadIdx.x] - v;  // exclusive
}

__global__ void scan3_kernel(int* __restrict__ offsets, int* __restrict__ cursor,
                             const int* __restrict__ partials, int n) {
    int i = blockIdx.x * 256 + threadIdx.x;
    if (i < n) {
        int o = offsets[i] + partials[blockIdx.x];
        offsets[i] = o;
        cursor[i]  = o;
    }
    if (i == 0) offsets[n] = NE;
}

// ---------------- reorder: sorted_src ----------------
__global__ void reorder_kernel(const int* __restrict__ ei, int* __restrict__ cursor,
                               int* __restrict__ ssrc) {
    int e = blockIdx.x * blockDim.x + threadIdx.x;
    if (e < NE) {
        int pos = atomicAdd(&cursor[ei[NE + e]], 1);
        ssrc[pos] = ei[e];
    }
}

// ---------------- stage combined weights: WT[n][k] bf16, k<128: Wl2, else Wr2 ----------------
__global__ void wt_stage_kernel(const float* __restrict__ Wl2,
                                const float* __restrict__ Wr2,
                                unsigned short* __restrict__ WT) {
    int t = blockIdx.x * blockDim.x + threadIdx.x;   // 0..32767
    if (t >= DD * 256) return;
    int n = t >> 8;
    int k = t & 255;
    float v = (k < DD) ? Wl2[n * DD + k] : Wr2[n * DD + (k - DD)];
    WT[t] = f2bf(v);
}

// ---------------- CSR aggregation + h: A[node] = [BN(mean relu) | BN(relu(x[node]))] bf16 ----------------
// one 64-lane wave per node; lane owns features {2l, 2l+1}. No atomics.
__global__ __launch_bounds__(256) void aggregate_kernel(
    const float* __restrict__ x, const int* __restrict__ offsets,
    const int* __restrict__ ssrc,
    const float* __restrict__ bn_gamma, const float* __restrict__ bn_beta,
    const float* __restrict__ bn_mean, const float* __restrict__ bn_var,
    unsigned short* __restrict__ A)
{
    const int node = blockIdx.x * 4 + (threadIdx.x >> 6);   // grid exact: NN/4 blocks
    const int l = threadIdx.x & 63;

    const float2 bm = *(const float2*)(bn_mean  + 2 * l);
    const float2 bv = *(const float2*)(bn_var   + 2 * l);
    const float2 bg = *(const float2*)(bn_gamma + 2 * l);
    const float2 bb = *(const float2*)(bn_beta  + 2 * l);
    const float s0c = rsqrtf(bv.x + 1e-5f) * bg.x;
    const float s1c = rsqrtf(bv.y + 1e-5f) * bg.y;

    const int st = offsets[node], en = offsets[node + 1];
    const float* xb = x + 2 * l;

    float s0 = 0.f, s1 = 0.f;
    int j = st;
    for (; j + 4 <= en; j += 4) {
        const int4 ss = *(const int4*)(ssrc + j);
        float2 v0 = *(const float2*)(xb + (size_t)ss.x * DD);
        float2 v1 = *(const float2*)(xb + (size_t)ss.y * DD);
        float2 v2 = *(const float2*)(xb + (size_t)ss.z * DD);
        float2 v3 = *(const float2*)(xb + (size_t)ss.w * DD);
        s0 += fmaxf(v0.x, 0.f) + fmaxf(v1.x, 0.f) + fmaxf(v2.x, 0.f) + fmaxf(v3.x, 0.f);
        s1 += fmaxf(v0.y, 0.f) + fmaxf(v1.y, 0.f) + fmaxf(v2.y, 0.f) + fmaxf(v3.y, 0.f);
    }
    for (; j < en; ++j) {
        int s = ssrc[j];
        float2 v = *(const float2*)(xb + (size_t)s * DD);
        s0 += fmaxf(v.x, 0.f);
        s1 += fmaxf(v.y, 0.f);
    }

    const int deg = en - st;
    float m0, m1;
    if (deg > 0) {
        float inv = 1.0f / (float)deg;
        m0 = (s0 * inv - bm.x) * s0c + bb.x;   // BN affine commutes with mean
        m1 = (s1 * inv - bm.y) * s1c + bb.y;
    } else {
        m0 = 0.f; m1 = 0.f;                    // reference: mean of empty segment = 0
    }

    // h for this node's own features (GEMM right operand)
    const float2 xv = *(const float2*)(xb + (size_t)node * DD);
    float h0 = (fmaxf(xv.x, 0.f) - bm.x) * s0c + bb.x;
    float h1 = (fmaxf(xv.y, 0.f) - bm.y) * s1c + bb.y;

    unsigned short* arow = A + (size_t)node * 256;
    *(ushort2*)(arow + 2 * l)       = make_ushort2(f2bf(m0), f2bf(m1));
    *(ushort2*)(arow + DD + 2 * l)  = make_ushort2(f2bf(h0), f2bf(h1));
}

// ---------------- MFMA GEMM + bias + L2 normalize ----------------
// out[i][n] = normalize( A[i][:] . WT[n][:] + bl[n] )
// block = 256 threads (4 waves), 16 rows; wave w owns col-tiles {2w, 2w+1}.
__global__ __launch_bounds__(256) void mfma_gemm_norm_kernel(
    const unsigned short* __restrict__ A, const unsigned short* __restrict__ WT,
    const float* __restrict__ bl, float* __restrict__ out)
{
    __shared__ float partial[4][16];

    const int wave = threadIdx.x >> 6;
    const int l    = threadIdx.x & 63;
    const int r    = l & 15;        // A row within tile / B col within tile
    const int seg  = l >> 4;        // k-segment selector
    const int row0 = blockIdx.x * 16;
    const int c0   = wave * 32;     // first col-tile base

    const unsigned short* ap  = A  + (size_t)(row0 + r) * 256 + seg * 8;
    const unsigned short* bp0 = WT + (size_t)(c0 + r) * 256 + seg * 8;
    const unsigned short* bp1 = WT + (size_t)(c0 + 16 + r) * 256 + seg * 8;

    f32x4 acc0 = {0.f, 0.f, 0.f, 0.f};
    f32x4 acc1 = {0.f, 0.f, 0.f, 0.f};

#pragma unroll
    for (int k = 0; k < 256; k += 32) {
        bf16x8 af = *(const bf16x8*)(ap + k);
        bf16x8 b0 = *(const bf16x8*)(bp0 + k);
        bf16x8 b1 = *(const bf16x8*)(bp1 + k);
        acc0 = __builtin_amdgcn_mfma_f32_16x16x32_bf16(af, b0, acc0, 0, 0, 0);
        acc1 = __builtin_amdgcn_mfma_f32_16x16x32_bf16(af, b1, acc1, 0, 0, 0);
    }

    // C/D layout: col = lane&15, row = (lane>>4)*4 + q  [m89-verified]
    const float bias0 = bl[c0 + r];
    const float bias1 = bl[c0 + 16 + r];
    float p[4];
#pragma unroll
    for (int q = 0; q < 4; ++q) {
        acc0[q] += bias0;
        acc1[q] += bias1;
        p[q] = acc0[q] * acc0[q] + acc1[q] * acc1[q];
    }
    // reduce across the 16 lanes of this seg (they hold different cols)
#pragma unroll
    for (int m = 1; m < 16; m <<= 1) {
#pragma unroll
        for (int q = 0; q < 4; ++q) p[q] += __shfl_xor(p[q], m);
    }
    if (r == 0) {
#pragma unroll
        for (int q = 0; q < 4; ++q) partial[wave][seg * 4 + q] = p[q];
    }
    __syncthreads();

#pragma unroll
    for (int q = 0; q < 4; ++q) {
        const int rr = seg * 4 + q;
        float s = partial[0][rr] + partial[1][rr] + partial[2][rr] + partial[3][rr];
        float inv = 1.0f / fmaxf(sqrtf(s), 1e-12f);
        float* orow = out + (size_t)(row0 + rr) * DD;
        orow[c0 + r]      = acc0[q] * inv;
        orow[c0 + 16 + r] = acc1[q] * inv;
    }
}

extern "C" void kernel_launch(void* const* d_in, const int* in_sizes, int n_in,
                              void* d_out, int out_size, void* d_ws, size_t ws_size,
                              hipStream_t stream) {
    const float* x        = (const float*)d_in[0];
    const int*   ei       = (const int*)d_in[1];
    const float* Wl2      = (const float*)d_in[5];
    const float* bl2      = (const float*)d_in[6];
    const float* Wr2      = (const float*)d_in[7];
    const float* bn_gamma = (const float*)d_in[8];
    const float* bn_beta  = (const float*)d_in[9];
    const float* bn_mean  = (const float*)d_in[10];
    const float* bn_var   = (const float*)d_in[11];
    float* out = (float*)d_out;

    // workspace layout
    unsigned short* A  = (unsigned short*)d_ws;             // NN*256 bf16 (51.2 MB)
    unsigned short* WT = A + (size_t)NN * 256;              // 128*256 bf16 (64 KB)
    int* counts   = (int*)(WT + DD * 256);                  // NN
    int* offsets  = counts + NN;                            // NN+1
    int* cursor   = offsets + NN + 1;                       // NN
    int* partials = cursor + NN;                            // 512
    int* ssrc     = partials + 512;                         // NE

    const int nb_nodes = (NN + 255) / 256;   // 391
    const int nb_edges = (NE + 255) / 256;

    zero_int_kernel<<<nb_nodes, 256, 0, stream>>>(counts, NN);
    hist_kernel<<<nb_edges, 256, 0, stream>>>(ei, counts);
    scan1_kernel<<<nb_nodes, 256, 0, stream>>>(counts, offsets, partials, NN);
    scan2_kernel<<<1, 512, 0, stream>>>(partials, nb_nodes);
    scan3_kernel<<<nb_nodes, 256, 0, stream>>>(offsets, cursor, partials, NN);
    reorder_kernel<<<nb_edges, 256, 0, stream>>>(ei, cursor, ssrc);
    wt_stage_kernel<<<(DD * 256 + 255) / 256, 256, 0, stream>>>(Wl2, Wr2, WT);
    aggregate_kernel<<<NN / 4, 256, 0, stream>>>(
        x, offsets, ssrc, bn_gamma, bn_beta, bn_mean, bn_var, A);
    mfma_gemm_norm_kernel<<<NN / 16, 256, 0, stream>>>(A, WT, bl2, out);
}

// Round 7
// 278.175 us; speedup vs baseline: 4.9698x; 1.1120x over previous
//
#include <hip/hip_runtime.h>
#include <math.h>

#define NN 100000
#define NE 600000
#define DD 128
#define NTILES 6250          // NN / 16
#define TPB 8                // row-tiles per block (GEMM)

typedef __attribute__((ext_vector_type(8))) __bf16 bf16x8;
typedef __attribute__((ext_vector_type(4))) float f32x4;

__device__ inline unsigned short f2bf(float f) {
    unsigned int u = __float_as_uint(f);
    unsigned int r = (u + 0x7fffu + ((u >> 16) & 1u)) >> 16;
    return (unsigned short)r;
}

// ---------------- zero ints ----------------
__global__ void zero_int_kernel(int* __restrict__ p, int n) {
    int i = blockIdx.x * blockDim.x + threadIdx.x;
    if (i < n) p[i] = 0;
}

// ---------------- histogram of dst ----------------
__global__ void hist_kernel(const int* __restrict__ ei, int* __restrict__ counts) {
    int e = blockIdx.x * blockDim.x + threadIdx.x;
    if (e < NE) atomicAdd(&counts[ei[NE + e]], 1);
}

// ---------------- two-level exclusive scan ----------------
__global__ __launch_bounds__(256) void scan1_kernel(const int* __restrict__ counts,
                                                    int* __restrict__ offsets,
                                                    int* __restrict__ partials, int n) {
    __shared__ int tmp[256];
    int i = blockIdx.x * 256 + threadIdx.x;
    int v = (i < n) ? counts[i] : 0;
    tmp[threadIdx.x] = v;
    __syncthreads();
    for (int off = 1; off < 256; off <<= 1) {
        int t = (threadIdx.x >= off) ? tmp[threadIdx.x - off] : 0;
        __syncthreads();
        tmp[threadIdx.x] += t;
        __syncthreads();
    }
    if (i < n) offsets[i] = tmp[threadIdx.x] - v;   // exclusive
    if (threadIdx.x == 255) partials[blockIdx.x] = tmp[255];
}

__global__ __launch_bounds__(512) void scan2_kernel(int* __restrict__ partials, int nb) {
    __shared__ int tmp[512];
    int v = (threadIdx.x < nb) ? partials[threadIdx.x] : 0;
    tmp[threadIdx.x] = v;
    __syncthreads();
    for (int off = 1; off < 512; off <<= 1) {
        int t = (threadIdx.x >= off) ? tmp[threadIdx.x - off] : 0;
        __syncthreads();
        tmp[threadIdx.x] += t;
        __syncthreads();
    }
    if (threadIdx.x < nb) partials[threadIdx.x] = tmp[threadIdx.x] - v;  // exclusive
}

__global__ void scan3_kernel(int* __restrict__ offsets, int* __restrict__ cursor,
                             const int* __restrict__ partials, int n) {
    int i = blockIdx.x * 256 + threadIdx.x;
    if (i < n) {
        int o = offsets[i] + partials[blockIdx.x];
        offsets[i] = o;
        cursor[i]  = o;
    }
    if (i == 0) offsets[n] = NE;
}

// ---------------- reorder: sorted_src ----------------
__global__ void reorder_kernel(const int* __restrict__ ei, int* __restrict__ cursor,
                               int* __restrict__ ssrc) {
    int e = blockIdx.x * blockDim.x + threadIdx.x;
    if (e < NE) {
        int pos = atomicAdd(&cursor[ei[NE + e]], 1);
        ssrc[pos] = ei[e];
    }
}

// ---------------- stage combined weights: WT[n][k] bf16, k<128: Wl2, else Wr2 ----------------
__global__ void wt_stage_kernel(const float* __restrict__ Wl2,
                                const float* __restrict__ Wr2,
                                unsigned short* __restrict__ WT) {
    int t = blockIdx.x * blockDim.x + threadIdx.x;   // 0..32767
    if (t >= DD * 256) return;
    int n = t >> 8;
    int k = t & 255;
    float v = (k < DD) ? Wl2[n * DD + k] : Wr2[n * DD + (k - DD)];
    WT[t] = f2bf(v);
}

// ---------------- CSR aggregation + h: A[node] = [BN(mean relu) | BN(relu(x[node]))] bf16 ----------------
// one 64-lane wave per node; lane owns features {2l, 2l+1}. No atomics.
__global__ __launch_bounds__(256) void aggregate_kernel(
    const float* __restrict__ x, const int* __restrict__ offsets,
    const int* __restrict__ ssrc,
    const float* __restrict__ bn_gamma, const float* __restrict__ bn_beta,
    const float* __restrict__ bn_mean, const float* __restrict__ bn_var,
    unsigned short* __restrict__ A)
{
    const int node = blockIdx.x * 4 + (threadIdx.x >> 6);   // grid exact: NN/4 blocks
    const int l = threadIdx.x & 63;

    const float2 bm = *(const float2*)(bn_mean  + 2 * l);
    const float2 bv = *(const float2*)(bn_var   + 2 * l);
    const float2 bg = *(const float2*)(bn_gamma + 2 * l);
    const float2 bb = *(const float2*)(bn_beta  + 2 * l);
    const float s0c = rsqrtf(bv.x + 1e-5f) * bg.x;
    const float s1c = rsqrtf(bv.y + 1e-5f) * bg.y;

    const int st = offsets[node], en = offsets[node + 1];
    const float* xb = x + 2 * l;

    float s0 = 0.f, s1 = 0.f;
    int j = st;
    for (; j + 4 <= en; j += 4) {
        const int4 ss = *(const int4*)(ssrc + j);
        float2 v0 = *(const float2*)(xb + (size_t)ss.x * DD);
        float2 v1 = *(const float2*)(xb + (size_t)ss.y * DD);
        float2 v2 = *(const float2*)(xb + (size_t)ss.z * DD);
        float2 v3 = *(const float2*)(xb + (size_t)ss.w * DD);
        s0 += fmaxf(v0.x, 0.f) + fmaxf(v1.x, 0.f) + fmaxf(v2.x, 0.f) + fmaxf(v3.x, 0.f);
        s1 += fmaxf(v0.y, 0.f) + fmaxf(v1.y, 0.f) + fmaxf(v2.y, 0.f) + fmaxf(v3.y, 0.f);
    }
    for (; j < en; ++j) {
        int s = ssrc[j];
        float2 v = *(const float2*)(xb + (size_t)s * DD);
        s0 += fmaxf(v.x, 0.f);
        s1 += fmaxf(v.y, 0.f);
    }

    const int deg = en - st;
    float m0, m1;
    if (deg > 0) {
        float inv = 1.0f / (float)deg;
        m0 = (s0 * inv - bm.x) * s0c + bb.x;   // BN affine commutes with mean
        m1 = (s1 * inv - bm.y) * s1c + bb.y;
    } else {
        m0 = 0.f; m1 = 0.f;                    // reference: mean of empty segment = 0
    }

    // h for this node's own features (GEMM right operand)
    const float2 xv = *(const float2*)(xb + (size_t)node * DD);
    float h0 = (fmaxf(xv.x, 0.f) - bm.x) * s0c + bb.x;
    float h1 = (fmaxf(xv.y, 0.f) - bm.y) * s1c + bb.y;

    unsigned short* arow = A + (size_t)node * 256;
    *(ushort2*)(arow + 2 * l)       = make_ushort2(f2bf(m0), f2bf(m1));
    *(ushort2*)(arow + DD + 2 * l)  = make_ushort2(f2bf(h0), f2bf(h1));
}

// ---------------- MFMA GEMM + bias + L2 normalize (v2: B-resident) ----------------
// out[i][n] = normalize( A[i][:] . WT[n][:] + bl[n] )
// block = 256 threads (4 waves). Wave w holds B frags for col-tiles {2w,2w+1}
// in registers for the whole kernel; loops TPB row-tiles of 16 rows.
__global__ __launch_bounds__(256) void mfma_gemm_norm_kernel(
    const unsigned short* __restrict__ A, const unsigned short* __restrict__ WT,
    const float* __restrict__ bl, float* __restrict__ out)
{
    __shared__ float partial[4][16];

    const int wave = threadIdx.x >> 6;
    const int l    = threadIdx.x & 63;
    const int r    = l & 15;        // A row within tile / B col within tile
    const int seg  = l >> 4;        // k-segment selector
    const int c0   = wave * 32;     // first col-tile base

    // persistent B fragments: 16 x bf16x8 = 64 VGPRs
    bf16x8 bf0[8], bf1[8];
    {
        const unsigned short* bp0 = WT + (size_t)(c0 + r) * 256 + seg * 8;
        const unsigned short* bp1 = WT + (size_t)(c0 + 16 + r) * 256 + seg * 8;
#pragma unroll
        for (int kk = 0; kk < 8; ++kk) {
            bf0[kk] = *(const bf16x8*)(bp0 + kk * 32);
            bf1[kk] = *(const bf16x8*)(bp1 + kk * 32);
        }
    }
    const float bias0 = bl[c0 + r];
    const float bias1 = bl[c0 + 16 + r];

    const int tend = min((int)(blockIdx.x + 1) * TPB, NTILES);
#pragma unroll 1
    for (int t = blockIdx.x * TPB; t < tend; ++t) {
        const int row0 = t * 16;
        const unsigned short* ap = A + (size_t)(row0 + r) * 256 + seg * 8;

        // 8 back-to-back 16B loads: real MLP
        bf16x8 af[8];
#pragma unroll
        for (int kk = 0; kk < 8; ++kk) af[kk] = *(const bf16x8*)(ap + kk * 32);

        f32x4 acc0 = {0.f, 0.f, 0.f, 0.f};
        f32x4 acc1 = {0.f, 0.f, 0.f, 0.f};
#pragma unroll
        for (int kk = 0; kk < 8; ++kk) {
            acc0 = __builtin_amdgcn_mfma_f32_16x16x32_bf16(af[kk], bf0[kk], acc0, 0, 0, 0);
            acc1 = __builtin_amdgcn_mfma_f32_16x16x32_bf16(af[kk], bf1[kk], acc1, 0, 0, 0);
        }

        // C/D layout: col = lane&15, row = (lane>>4)*4 + q  [m89-verified]
        float p[4];
#pragma unroll
        for (int q = 0; q < 4; ++q) {
            acc0[q] += bias0;
            acc1[q] += bias1;
            p[q] = acc0[q] * acc0[q] + acc1[q] * acc1[q];
        }
#pragma unroll
        for (int m = 1; m < 16; m <<= 1) {
#pragma unroll
            for (int q = 0; q < 4; ++q) p[q] += __shfl_xor(p[q], m);
        }
        if (r == 0) {
#pragma unroll
            for (int q = 0; q < 4; ++q) partial[wave][seg * 4 + q] = p[q];
        }
        __syncthreads();

#pragma unroll
        for (int q = 0; q < 4; ++q) {
            const int rr = seg * 4 + q;
            float s = partial[0][rr] + partial[1][rr] + partial[2][rr] + partial[3][rr];
            float inv = 1.0f / fmaxf(sqrtf(s), 1e-12f);
            float* orow = out + (size_t)(row0 + rr) * DD;
            orow[c0 + r]      = acc0[q] * inv;
            orow[c0 + 16 + r] = acc1[q] * inv;
        }
        __syncthreads();   // protect partial[] before next tile overwrites
    }
}

extern "C" void kernel_launch(void* const* d_in, const int* in_sizes, int n_in,
                              void* d_out, int out_size, void* d_ws, size_t ws_size,
                              hipStream_t stream) {
    const float* x        = (const float*)d_in[0];
    const int*   ei       = (const int*)d_in[1];
    const float* Wl2      = (const float*)d_in[5];
    const float* bl2      = (const float*)d_in[6];
    const float* Wr2      = (const float*)d_in[7];
    const float* bn_gamma = (const float*)d_in[8];
    const float* bn_beta  = (const float*)d_in[9];
    const float* bn_mean  = (const float*)d_in[10];
    const float* bn_var   = (const float*)d_in[11];
    float* out = (float*)d_out;

    // workspace layout
    unsigned short* A  = (unsigned short*)d_ws;             // NN*256 bf16 (51.2 MB)
    unsigned short* WT = A + (size_t)NN * 256;              // 128*256 bf16 (64 KB)
    int* counts   = (int*)(WT + DD * 256);                  // NN
    int* offsets  = counts + NN;                            // NN+1
    int* cursor   = offsets + NN + 1;                       // NN
    int* partials = cursor + NN;                            // 512
    int* ssrc     = partials + 512;                         // NE

    const int nb_nodes = (NN + 255) / 256;   // 391
    const int nb_edges = (NE + 255) / 256;

    zero_int_kernel<<<nb_nodes, 256, 0, stream>>>(counts, NN);
    hist_kernel<<<nb_edges, 256, 0, stream>>>(ei, counts);
    scan1_kernel<<<nb_nodes, 256, 0, stream>>>(counts, offsets, partials, NN);
    scan2_kernel<<<1, 512, 0, stream>>>(partials, nb_nodes);
    scan3_kernel<<<nb_nodes, 256, 0, stream>>>(offsets, cursor, partials, NN);
    reorder_kernel<<<nb_edges, 256, 0, stream>>>(ei, cursor, ssrc);
    wt_stage_kernel<<<(DD * 256 + 255) / 256, 256, 0, stream>>>(Wl2, Wr2, WT);
    aggregate_kernel<<<NN / 4, 256, 0, stream>>>(
        x, offsets, ssrc, bn_gamma, bn_beta, bn_mean, bn_var, A);
    const int gemm_blocks = (NTILES + TPB - 1) / TPB;   // 782
    mfma_gemm_norm_kernel<<<gemm_blocks, 256, 0, stream>>>(A, WT, bl2, out);
}

// Round 11
// 266.715 us; speedup vs baseline: 5.1833x; 1.0430x over previous
//
#include <hip/hip_runtime.h>
#include <math.h>

#define NN 100000
#define NE 600000
#define DD 128
#define NTILES 6250          // NN / 16
#define TPB 8                // row-tiles per block (GEMM)

typedef __attribute__((ext_vector_type(8))) __bf16 bf16x8;
typedef __attribute__((ext_vector_type(4))) float f32x4;

__device__ inline unsigned short f2bf(float f) {
    unsigned int u = __float_as_uint(f);
    unsigned int r = (u + 0x7fffu + ((u >> 16) & 1u)) >> 16;
    return (unsigned short)r;
}

// ---------------- histogram of dst ----------------
__global__ void hist_kernel(const int* __restrict__ ei, int* __restrict__ counts) {
    int e = blockIdx.x * blockDim.x + threadIdx.x;
    if (e < NE) atomicAdd(&counts[ei[NE + e]], 1);
}

// ---------------- two-level exclusive scan ----------------
__global__ __launch_bounds__(256) void scan1_kernel(const int* __restrict__ counts,
                                                    int* __restrict__ offsets,
                                                    int* __restrict__ partials, int n) {
    __shared__ int tmp[256];
    int i = blockIdx.x * 256 + threadIdx.x;
    int v = (i < n) ? counts[i] : 0;
    tmp[threadIdx.x] = v;
    __syncthreads();
    for (int off = 1; off < 256; off <<= 1) {
        int t = (threadIdx.x >= off) ? tmp[threadIdx.x - off] : 0;
        __syncthreads();
        tmp[threadIdx.x] += t;
        __syncthreads();
    }
    if (i < n) offsets[i] = tmp[threadIdx.x] - v;   // exclusive
    if (threadIdx.x == 255) partials[blockIdx.x] = tmp[255];
}

__global__ __launch_bounds__(512) void scan2_kernel(int* __restrict__ partials, int nb) {
    __shared__ int tmp[512];
    int v = (threadIdx.x < nb) ? partials[threadIdx.x] : 0;
    tmp[threadIdx.x] = v;
    __syncthreads();
    for (int off = 1; off < 512; off <<= 1) {
        int t = (threadIdx.x >= off) ? tmp[threadIdx.x - off] : 0;
        __syncthreads();
        tmp[threadIdx.x] += t;
        __syncthreads();
    }
    if (threadIdx.x < nb) partials[threadIdx.x] = tmp[threadIdx.x] - v;  // exclusive
}

__global__ void scan3_kernel(int* __restrict__ offsets, int* __restrict__ cursor,
                             const int* __restrict__ partials, int n) {
    int i = blockIdx.x * 256 + threadIdx.x;
    if (i < n) {
        int o = offsets[i] + partials[blockIdx.x];
        offsets[i] = o;
        cursor[i]  = o;
    }
    if (i == 0) offsets[n] = NE;
}

// ---------------- reorder: sorted_src ----------------
__global__ void reorder_kernel(const int* __restrict__ ei, int* __restrict__ cursor,
                               int* __restrict__ ssrc) {
    int e = blockIdx.x * blockDim.x + threadIdx.x;
    if (e < NE) {
        int pos = atomicAdd(&cursor[ei[NE + e]], 1);
        ssrc[pos] = ei[e];
    }
}

// ---------------- stage combined weights: WT[n][k] bf16, k<128: Wl2, else Wr2 ----------------
__global__ void wt_stage_kernel(const float* __restrict__ Wl2,
                                const float* __restrict__ Wr2,
                                unsigned short* __restrict__ WT) {
    int t = blockIdx.x * blockDim.x + threadIdx.x;   // 0..32767
    if (t >= DD * 256) return;
    int n = t >> 8;
    int k = t & 255;
    float v = (k < DD) ? Wl2[n * DD + k] : Wr2[n * DD + (k - DD)];
    WT[t] = f2bf(v);
}

// ---------------- CSR aggregation + h (v2: half-wave per node, float4/lane) ----------------
// 32-lane group owns one node; lane owns features {4l..4l+3}. One dwordx4
// wave-instruction gathers TWO rows (one per half-wave). No atomics.
__global__ __launch_bounds__(256) void aggregate_kernel(
    const float* __restrict__ x, const int* __restrict__ offsets,
    const int* __restrict__ ssrc,
    const float* __restrict__ bn_gamma, const float* __restrict__ bn_beta,
    const float* __restrict__ bn_mean, const float* __restrict__ bn_var,
    unsigned short* __restrict__ A)
{
    const int node = blockIdx.x * 8 + (threadIdx.x >> 5);   // grid exact: NN/8 blocks
    const int l = threadIdx.x & 31;
    const int c = l * 4;

    const float4 bm = *(const float4*)(bn_mean  + c);
    const float4 bv = *(const float4*)(bn_var   + c);
    const float4 bg = *(const float4*)(bn_gamma + c);
    const float4 bb = *(const float4*)(bn_beta  + c);
    const float sc0 = rsqrtf(bv.x + 1e-5f) * bg.x;
    const float sc1 = rsqrtf(bv.y + 1e-5f) * bg.y;
    const float sc2 = rsqrtf(bv.z + 1e-5f) * bg.z;
    const float sc3 = rsqrtf(bv.w + 1e-5f) * bg.w;

    const int st = offsets[node], en = offsets[node + 1];
    const float* xb = x + c;

    float s0 = 0.f, s1 = 0.f, s2 = 0.f, s3 = 0.f;
    int j = st;
    for (; j + 4 <= en; j += 4) {
        const int4 ss = *(const int4*)(ssrc + j);
        float4 v0 = *(const float4*)(xb + (size_t)ss.x * DD);
        float4 v1 = *(const float4*)(xb + (size_t)ss.y * DD);
        float4 v2 = *(const float4*)(xb + (size_t)ss.z * DD);
        float4 v3 = *(const float4*)(xb + (size_t)ss.w * DD);
        s0 += fmaxf(v0.x, 0.f) + fmaxf(v1.x, 0.f) + fmaxf(v2.x, 0.f) + fmaxf(v3.x, 0.f);
        s1 += fmaxf(v0.y, 0.f) + fmaxf(v1.y, 0.f) + fmaxf(v2.y, 0.f) + fmaxf(v3.y, 0.f);
        s2 += fmaxf(v0.z, 0.f) + fmaxf(v1.z, 0.f) + fmaxf(v2.z, 0.f) + fmaxf(v3.z, 0.f);
        s3 += fmaxf(v0.w, 0.f) + fmaxf(v1.w, 0.f) + fmaxf(v2.w, 0.f) + fmaxf(v3.w, 0.f);
    }
    for (; j < en; ++j) {
        int s = ssrc[j];
        float4 v = *(const float4*)(xb + (size_t)s * DD);
        s0 += fmaxf(v.x, 0.f);
        s1 += fmaxf(v.y, 0.f);
        s2 += fmaxf(v.z, 0.f);
        s3 += fmaxf(v.w, 0.f);
    }

    const int deg = en - st;
    float m0, m1, m2, m3;
    if (deg > 0) {
        float inv = 1.0f / (float)deg;
        m0 = (s0 * inv - bm.x) * sc0 + bb.x;   // BN affine commutes with mean
        m1 = (s1 * inv - bm.y) * sc1 + bb.y;
        m2 = (s2 * inv - bm.z) * sc2 + bb.z;
        m3 = (s3 * inv - bm.w) * sc3 + bb.w;
    } else {
        m0 = m1 = m2 = m3 = 0.f;               // reference: empty segment -> 0
    }

    // h for this node's own features (GEMM right operand)
    const float4 xv = *(const float4*)(xb + (size_t)node * DD);
    float h0 = (fmaxf(xv.x, 0.f) - bm.x) * sc0 + bb.x;
    float h1 = (fmaxf(xv.y, 0.f) - bm.y) * sc1 + bb.y;
    float h2 = (fmaxf(xv.z, 0.f) - bm.z) * sc2 + bb.z;
    float h3 = (fmaxf(xv.w, 0.f) - bm.w) * sc3 + bb.w;

    unsigned short* arow = A + (size_t)node * 256;
    ushort4 mm; mm.x = f2bf(m0); mm.y = f2bf(m1); mm.z = f2bf(m2); mm.w = f2bf(m3);
    ushort4 hh; hh.x = f2bf(h0); hh.y = f2bf(h1); hh.z = f2bf(h2); hh.w = f2bf(h3);
    *(ushort4*)(arow + c)      = mm;
    *(ushort4*)(arow + DD + c) = hh;
}

// ---------------- MFMA GEMM + bias + L2 normalize (B-resident) ----------------
// out[i][n] = normalize( A[i][:] . WT[n][:] + bl[n] )
// block = 256 threads (4 waves). Wave w holds B frags for col-tiles {2w,2w+1}
// in registers for the whole kernel; loops TPB row-tiles of 16 rows.
__global__ __launch_bounds__(256) void mfma_gemm_norm_kernel(
    const unsigned short* __restrict__ A, const unsigned short* __restrict__ WT,
    const float* __restrict__ bl, float* __restrict__ out)
{
    __shared__ float partial[4][16];

    const int wave = threadIdx.x >> 6;
    const int l    = threadIdx.x & 63;
    const int r    = l & 15;        // A row within tile / B col within tile
    const int seg  = l >> 4;        // k-segment selector
    const int c0   = wave * 32;     // first col-tile base

    // persistent B fragments: 16 x bf16x8 = 64 VGPRs
    bf16x8 bf0[8], bf1[8];
    {
        const unsigned short* bp0 = WT + (size_t)(c0 + r) * 256 + seg * 8;
        const unsigned short* bp1 = WT + (size_t)(c0 + 16 + r) * 256 + seg * 8;
#pragma unroll
        for (int kk = 0; kk < 8; ++kk) {
            bf0[kk] = *(const bf16x8*)(bp0 + kk * 32);
            bf1[kk] = *(const bf16x8*)(bp1 + kk * 32);
        }
    }
    const float bias0 = bl[c0 + r];
    const float bias1 = bl[c0 + 16 + r];

    const int tend = min((int)(blockIdx.x + 1) * TPB, NTILES);
#pragma unroll 1
    for (int t = blockIdx.x * TPB; t < tend; ++t) {
        const int row0 = t * 16;
        const unsigned short* ap = A + (size_t)(row0 + r) * 256 + seg * 8;

        // 8 back-to-back 16B loads: real MLP
        bf16x8 af[8];
#pragma unroll
        for (int kk = 0; kk < 8; ++kk) af[kk] = *(const bf16x8*)(ap + kk * 32);

        f32x4 acc0 = {0.f, 0.f, 0.f, 0.f};
        f32x4 acc1 = {0.f, 0.f, 0.f, 0.f};
#pragma unroll
        for (int kk = 0; kk < 8; ++kk) {
            acc0 = __builtin_amdgcn_mfma_f32_16x16x32_bf16(af[kk], bf0[kk], acc0, 0, 0, 0);
            acc1 = __builtin_amdgcn_mfma_f32_16x16x32_bf16(af[kk], bf1[kk], acc1, 0, 0, 0);
        }

        // C/D layout: col = lane&15, row = (lane>>4)*4 + q  [m89-verified]
        float p[4];
#pragma unroll
        for (int q = 0; q < 4; ++q) {
            acc0[q] += bias0;
            acc1[q] += bias1;
            p[q] = acc0[q] * acc0[q] + acc1[q] * acc1[q];
        }
#pragma unroll
        for (int m = 1; m < 16; m <<= 1) {
#pragma unroll
            for (int q = 0; q < 4; ++q) p[q] += __shfl_xor(p[q], m);
        }
        if (r == 0) {
#pragma unroll
            for (int q = 0; q < 4; ++q) partial[wave][seg * 4 + q] = p[q];
        }
        __syncthreads();

#pragma unroll
        for (int q = 0; q < 4; ++q) {
            const int rr = seg * 4 + q;
            float s = partial[0][rr] + partial[1][rr] + partial[2][rr] + partial[3][rr];
            float inv = 1.0f / fmaxf(sqrtf(s), 1e-12f);
            float* orow = out + (size_t)(row0 + rr) * DD;
            orow[c0 + r]      = acc0[q] * inv;
            orow[c0 + 16 + r] = acc1[q] * inv;
        }
        __syncthreads();   // protect partial[] before next tile overwrites
    }
}

extern "C" void kernel_launch(void* const* d_in, const int* in_sizes, int n_in,
                              void* d_out, int out_size, void* d_ws, size_t ws_size,
                              hipStream_t stream) {
    const float* x        = (const float*)d_in[0];
    const int*   ei       = (const int*)d_in[1];
    const float* Wl2      = (const float*)d_in[5];
    const float* bl2      = (const float*)d_in[6];
    const float* Wr2      = (const float*)d_in[7];
    const float* bn_gamma = (const float*)d_in[8];
    const float* bn_beta  = (const float*)d_in[9];
    const float* bn_mean  = (const float*)d_in[10];
    const float* bn_var   = (const float*)d_in[11];
    float* out = (float*)d_out;

    // workspace layout
    unsigned short* A  = (unsigned short*)d_ws;             // NN*256 bf16 (51.2 MB)
    unsigned short* WT = A + (size_t)NN * 256;              // 128*256 bf16 (64 KB)
    int* counts   = (int*)(WT + DD * 256);                  // NN
    int* offsets  = counts + NN;                            // NN+1
    int* cursor   = offsets + NN + 1;                       // NN
    int* partials = cursor + NN;                            // 512
    int* ssrc     = partials + 512;                         // NE

    const int nb_nodes = (NN + 255) / 256;   // 391
    const int nb_edges = (NE + 255) / 256;

    hipMemsetAsync(counts, 0, NN * sizeof(int), stream);    // zero histogram
    hist_kernel<<<nb_edges, 256, 0, stream>>>(ei, counts);
    scan1_kernel<<<nb_nodes, 256, 0, stream>>>(counts, offsets, partials, NN);
    scan2_kernel<<<1, 512, 0, stream>>>(partials, nb_nodes);
    scan3_kernel<<<nb_nodes, 256, 0, stream>>>(offsets, cursor, partials, NN);
    reorder_kernel<<<nb_edges, 256, 0, stream>>>(ei, cursor, ssrc);
    wt_stage_kernel<<<(DD * 256 + 255) / 256, 256, 0, stream>>>(Wl2, Wr2, WT);
    aggregate_kernel<<<NN / 8, 256, 0, stream>>>(
        x, offsets, ssrc, bn_gamma, bn_beta, bn_mean, bn_var, A);
    const int gemm_blocks = (NTILES + TPB - 1) / TPB;   // 782
    mfma_gemm_norm_kernel<<<gemm_blocks, 256, 0, stream>>>(A, WT, bl2, out);
}